// Round 10
// baseline (208.665 us; speedup 1.0000x reference)
//
#include <hip/hip_runtime.h>

#define HW   9216
#define IMG  96
#define NB   8
#define NK   4

typedef __bf16 bf16x8 __attribute__((ext_vector_type(8)));
typedef float  f32x4  __attribute__((ext_vector_type(4)));

__device__ __forceinline__ unsigned short f2bf(float f) {
    unsigned int u = __float_as_uint(f);
    u += 0x7FFFu + ((u >> 16) & 1u);   // round-to-nearest-even (finite inputs)
    return (unsigned short)(u >> 16);
}

// ---------------------------------------------------------------------------
// Kernel 1: prep (+ folded Wc->bf16 conversion in trailing 32 blocks).
// 512 threads = 8 waves/block, 32 channels per strip. This round: load
// batches deepened 8 -> 16 (VGPR 52 -> ~60, cap 64 at 8 waves/EU) so each
// wave keeps 4 KB in flight per batch instead of 2 KB.
// ---------------------------------------------------------------------------
extern "C" __global__ __launch_bounds__(512, 8)
void prep_kernel(const float* __restrict__ x,
                 const float* __restrict__ Wc,
                 const float* __restrict__ Woff,
                 const float* __restrict__ boff,
                 const float* __restrict__ Wwt,
                 const float* __restrict__ bwt,
                 unsigned short* __restrict__ xbt,
                 unsigned short* __restrict__ Wcb,
                 float2* __restrict__ coords,
                 float* __restrict__ wts)
{
    __shared__ __align__(16) unsigned short tile[64 * 266];   // 34048 B

    const int t   = threadIdx.x;
    const int bxr = blockIdx.x;

    if (bxr >= NB * 144) {
        // Wc fp32 -> bf16, row-major [o][c]. 65536 floats / (512*4) = 32 blocks.
        int u = ((bxr - NB * 144) * 512 + t) * 4;
        float4 v = *(const float4*)(Wc + u);
        union { unsigned short h[4]; int2 p; } pk;
        pk.h[0] = f2bf(v.x); pk.h[1] = f2bf(v.y);
        pk.h[2] = f2bf(v.z); pk.h[3] = f2bf(v.w);
        *(int2*)(Wcb + u) = pk.p;
        return;
    }

    const int b  = bxr / 144;
    const int p0 = (bxr % 144) * 64;
    const int px = t & 63;
    const int g  = __builtin_amdgcn_readfirstlane(t >> 6);  // wave strip 0..7

    float acc[12];
    #pragma unroll
    for (int j = 0; j < 12; ++j) acc[j] = 0.f;

    const float* xb = x + ((size_t)(b * 256 + g * 32)) * HW + p0 + px;
    unsigned int* trow = (unsigned int*)tile;

    #pragma unroll 1
    for (int i0 = 0; i0 < 32; i0 += 16) {
        float v[16];
        #pragma unroll
        for (int q = 0; q < 16; ++q)
            v[q] = xb[(size_t)(i0 + q) * HW];     // 16 independent loads in flight
        #pragma unroll
        for (int q = 0; q < 16; ++q) {
            const int c = g * 32 + i0 + q;        // wave-uniform -> scalar wt loads
            #pragma unroll
            for (int j = 0; j < 8; ++j) acc[j] += v[q] * Woff[j * 256 + c];
            #pragma unroll
            for (int j = 0; j < 4; ++j) acc[8 + j] += v[q] * Wwt[j * 256 + c];
        }
        #pragma unroll
        for (int q = 0; q < 16; q += 2) {
            unsigned int pk = (unsigned int)f2bf(v[q]) | ((unsigned int)f2bf(v[q + 1]) << 16);
            trow[px * 133 + ((g * 32 + i0 + q) >> 1)] = pk;
        }
    }

    __syncthreads();
    // pack xbt: 64 px x 256 c bf16, int4 stores (lanes 0-31 = contiguous 512 B)
    #pragma unroll
    for (int r = 0; r < 4; ++r) {
        int u = t + 512 * r;
        int sub = u & 31, p2 = u >> 5;
        int4 v = *(const int4*)(tile + p2 * 266 + sub * 8);
        *(int4*)(xbt + ((size_t)b * HW + p0 + p2) * 256 + sub * 8) = v;
    }
    __syncthreads();

    // cross-wave partial-dot reduction through re-used tile memory (24576 B)
    float* red = (float*)tile;
    #pragma unroll
    for (int j = 0; j < 12; ++j)
        red[(g * 64 + px) * 12 + j] = acc[j];
    __syncthreads();

    if (t < 64) {
        float s[12];
        #pragma unroll
        for (int j = 0; j < 12; ++j) {
            float sj = 0.f;
            #pragma unroll
            for (int w = 0; w < 8; ++w)
                sj += red[(w * 64 + px) * 12 + j];
            s[j] = sj;
        }

        const int p = p0 + px;
        const float pyf = (float)(p / IMG);
        const float pxf = (float)(p % IMG);

        #pragma unroll
        for (int k = 0; k < NK; ++k) {
            float fx = s[k * 2 + 0] + boff[k * 2 + 0];
            float fy = s[k * 2 + 1] + boff[k * 2 + 1];
            float vx = 2.0f * (pxf + fx) / 95.0f - 1.0f;
            float vy = 2.0f * (pyf + fy) / 95.0f - 1.0f;
            float ix = (vx + 1.0f) * 48.0f - 0.5f;
            float iy = (vy + 1.0f) * 48.0f - 0.5f;
            coords[((size_t)k * NB + b) * HW + p] = make_float2(ix, iy);
        }
        float l0 = s[8] + bwt[0], l1 = s[9] + bwt[1];
        float l2 = s[10] + bwt[2], l3 = s[11] + bwt[3];
        float m = fmaxf(fmaxf(l0, l1), fmaxf(l2, l3));
        float e0 = __expf(l0 - m), e1 = __expf(l1 - m);
        float e2 = __expf(l2 - m), e3 = __expf(l3 - m);
        float inv = 1.0f / (e0 + e1 + e2 + e3);
        wts[((size_t)0 * NB + b) * HW + p] = e0 * inv;
        wts[((size_t)1 * NB + b) * HW + p] = e1 * inv;
        wts[((size_t)2 * NB + b) * HW + p] = e2 * inv;
        wts[((size_t)3 * NB + b) * HW + p] = e3 * inv;
    }
}

// ---------------------------------------------------------------------------
// Kernel 2 (FUSED sample+gemm), v7: r9 + pipelined phase B (named regs).
//   Phase B: 2-stage pipeline, 8-corner groups held in INDIVIDUALLY NAMED
//   int4 registers (rule #20: no arrays the allocator can demote), rep loop
//   pinned with "#pragma unroll 1" (r8's spill came from compiler-unrolling
//   the loop and multiplying the buffer state). While group A is consumed,
//   group B's 8 loads are in flight; A is reissued for px+8 right after its
//   last use. ~125 VGPR expected, under the 168 cap at 3 waves/EU.
//   Phase C: wave-local As staging, barrier-free K-loop (r7, verified).
// LDS 49408 B -> 3 blocks/CU. XCD-chunked block swizzle.
// ---------------------------------------------------------------------------
extern "C" __global__ __launch_bounds__(256, 3)
void fused_kernel(const unsigned short* __restrict__ Wcb,
                  const unsigned short* __restrict__ xbt,
                  const float2* __restrict__ coords,
                  const float* __restrict__ wts,
                  const float* __restrict__ bc,
                  float* __restrict__ out)
{
    __shared__ __align__(16) unsigned char lds[49408];
    unsigned short* BsU   = (unsigned short*)lds;             // [64][256] bf16 swz
    unsigned short* AsU   = (unsigned short*)(lds + 32768);   // 4 x [64][32] per-wave
    float*          cw    = (float*)(lds + 32768);            // [64][16] w   (A/B, aliases As)
    unsigned int*   ci    = (unsigned int*)(lds + 36864);     // [64][8] idx  (A/B, aliases As)
    float*          wsumL = (float*)(lds + 49152);            // [64] (NOT aliased)

    const int t  = threadIdx.x;
    const int bx = blockIdx.x;
    const int b  = bx & 7;            // XCD-chunked: one batch per XCD
    const int p0 = (bx >> 3) * 64;    // p tile (o tile = full 256)

    // ---------------- phase A: per-(pixel,k) coords/weights ----------------
    {
        const int px = t & 63;
        const int k  = t >> 6;
        const int p  = p0 + px;
        float2 cc = coords[((size_t)k * NB + b) * HW + p];
        float wk  = wts[((size_t)k * NB + b) * HW + p];
        float x0f = floorf(cc.x), y0f = floorf(cc.y);
        float wx1 = cc.x - x0f, wx0 = 1.0f - wx1;
        float wy1 = cc.y - y0f, wy0 = 1.0f - wy1;
        int x0 = (int)x0f, y0 = (int)y0f;
        int x1 = x0 + 1,   y1 = y0 + 1;
        float vx0 = (x0 >= 0 && x0 < IMG) ? 1.f : 0.f;
        float vx1 = (x1 >= 0 && x1 < IMG) ? 1.f : 0.f;
        float vy0 = (y0 >= 0 && y0 < IMG) ? 1.f : 0.f;
        float vy1 = (y1 >= 0 && y1 < IMG) ? 1.f : 0.f;
        int cx0 = min(max(x0, 0), IMG - 1), cx1 = min(max(x1, 0), IMG - 1);
        int cy0 = min(max(y0, 0), IMG - 1), cy1 = min(max(y1, 0), IMG - 1);
        int i0 = cy0 * IMG + cx0, i1 = cy0 * IMG + cx1;
        int i2 = cy1 * IMG + cx0, i3 = cy1 * IMG + cx1;
        float w0 = wk * wx0 * wy0 * vx0 * vy0;
        float w1 = wk * wx1 * wy0 * vx1 * vy0;
        float w2 = wk * wx0 * wy1 * vx0 * vy1;
        float w3 = wk * wx1 * wy1 * vx1 * vy1;
        *(float4*)(cw + px * 16 + k * 4) = make_float4(w0, w1, w2, w3);
        uint2 ip;
        ip.x = (unsigned int)i0 | ((unsigned int)i1 << 16);
        ip.y = (unsigned int)i2 | ((unsigned int)i3 << 16);
        *(uint2*)(ci + px * 8 + k * 2) = ip;
    }
    __syncthreads();

    // ---------------- phase B: pipelined gather -> Bs (swizzled) -----------
    {
        if (t < 64) {
            float s = 0.f;
            #pragma unroll
            for (int j = 0; j < 16; ++j) s += cw[t * 16 + j];
            wsumL[t] = s;
        }
        const int pxl = t >> 5, ch = t & 31;
        const unsigned short* gbase = xbt + (size_t)b * HW * 256 + ch * 8;

        int4 A0, A1, A2, A3, A4, A5, A6, A7;   // group 0 (corners 0-7)
        int4 B0, B1, B2, B3, B4, B5, B6, B7;   // group 1 (corners 8-15)
        float wa[8], wb[8];                    // static-indexed only

#define ISSUE_G(V0,V1,V2,V3,V4,V5,V6,V7, WL, PX, GRP)                          \
        do {                                                                   \
            uint4 iv_ = *(const uint4*)(ci + (PX) * 8 + (GRP) * 4);            \
            V0 = *(const int4*)(gbase + (size_t)(iv_.x & 0xFFFFu) * 256);      \
            V1 = *(const int4*)(gbase + (size_t)(iv_.x >> 16)     * 256);      \
            V2 = *(const int4*)(gbase + (size_t)(iv_.y & 0xFFFFu) * 256);      \
            V3 = *(const int4*)(gbase + (size_t)(iv_.y >> 16)     * 256);      \
            V4 = *(const int4*)(gbase + (size_t)(iv_.z & 0xFFFFu) * 256);      \
            V5 = *(const int4*)(gbase + (size_t)(iv_.z >> 16)     * 256);      \
            V6 = *(const int4*)(gbase + (size_t)(iv_.w & 0xFFFFu) * 256);      \
            V7 = *(const int4*)(gbase + (size_t)(iv_.w >> 16)     * 256);      \
            float4 w0_ = *(const float4*)(cw + (PX) * 16 + (GRP) * 8);         \
            float4 w1_ = *(const float4*)(cw + (PX) * 16 + (GRP) * 8 + 4);     \
            (WL)[0] = w0_.x; (WL)[1] = w0_.y; (WL)[2] = w0_.z; (WL)[3] = w0_.w;\
            (WL)[4] = w1_.x; (WL)[5] = w1_.y; (WL)[6] = w1_.z; (WL)[7] = w1_.w;\
        } while (0)

#define CONS1(V, WJ, ACC)                                                      \
        do {                                                                   \
            const unsigned int* u_ = (const unsigned int*)&(V);                \
            _Pragma("unroll")                                                  \
            for (int q_ = 0; q_ < 4; ++q_) {                                   \
                (ACC)[2 * q_ + 0] += (WJ) * __uint_as_float(u_[q_] << 16);     \
                (ACC)[2 * q_ + 1] += (WJ) * __uint_as_float(u_[q_] & 0xFFFF0000u); \
            }                                                                  \
        } while (0)

        ISSUE_G(A0,A1,A2,A3,A4,A5,A6,A7, wa, pxl, 0);
        ISSUE_G(B0,B1,B2,B3,B4,B5,B6,B7, wb, pxl, 1);

        #pragma unroll 1
        for (int rep = 0; rep < 8; ++rep) {
            const int px  = rep * 8 + pxl;
            const int pxn = px + 8;
            float acc[8];
            #pragma unroll
            for (int i = 0; i < 8; ++i) acc[i] = 0.f;

            CONS1(A0, wa[0], acc); CONS1(A1, wa[1], acc);
            CONS1(A2, wa[2], acc); CONS1(A3, wa[3], acc);
            CONS1(A4, wa[4], acc); CONS1(A5, wa[5], acc);
            CONS1(A6, wa[6], acc); CONS1(A7, wa[7], acc);
            if (rep < 7)
                ISSUE_G(A0,A1,A2,A3,A4,A5,A6,A7, wa, pxn, 0);  // refill A; B in flight

            CONS1(B0, wb[0], acc); CONS1(B1, wb[1], acc);
            CONS1(B2, wb[2], acc); CONS1(B3, wb[3], acc);
            CONS1(B4, wb[4], acc); CONS1(B5, wb[5], acc);
            CONS1(B6, wb[6], acc); CONS1(B7, wb[7], acc);
            if (rep < 7)
                ISSUE_G(B0,B1,B2,B3,B4,B5,B6,B7, wb, pxn, 1);  // refill B

            union { unsigned short h[8]; int4 v4; } pk;
            #pragma unroll
            for (int i = 0; i < 8; ++i) pk.h[i] = f2bf(acc[i]);
            const int pos = ch ^ (px & 7);
            *(int4*)(BsU + px * 256 + pos * 8) = pk.v4;
        }
#undef ISSUE_G
#undef CONS1
    }
    __syncthreads();   // cw/ci dead; Bs complete. NO MORE BARRIERS below.

    // ---------------- phase C: barrier-free K-loop, wave-local As ----------
    const int lane = t & 63, wave = t >> 6;
    const int wm = wave * 64;          // this wave's 64 o-rows
    const int l15 = lane & 15, quad = lane >> 4;

    // this wave's private As quarter: [64 rows][32 k] bf16 = 4 KB
    unsigned short* AsW = AsU + wave * 2048;

    f32x4 acc[4][4];
    #pragma unroll
    for (int mt = 0; mt < 4; ++mt)
        #pragma unroll
        for (int nt = 0; nt < 4; ++nt)
            acc[mt][nt] = (f32x4){0.f, 0.f, 0.f, 0.f};

#define STAGE_A(K0)                                                            \
    do {                                                                       \
        _Pragma("unroll")                                                      \
        for (int i_ = 0; i_ < 4; ++i_) {                                       \
            int u_ = lane + 64 * i_;                                           \
            int row_ = u_ >> 2, sub_ = u_ & 3;                                 \
            int subg_ = sub_ ^ ((row_ >> 1) & 3);                              \
            __builtin_amdgcn_global_load_lds(                                  \
                (const __attribute__((address_space(1))) void*)(               \
                    Wcb + (size_t)(wm + row_) * 256 + (K0) + subg_ * 8),       \
                (__attribute__((address_space(3))) void*)(AsW + u_ * 8),       \
                16, 0, 0);                                                     \
        }                                                                      \
    } while (0)

    STAGE_A(0);
    for (int k0 = 0; k0 < 256; k0 += 32) {
        asm volatile("s_waitcnt vmcnt(0)" ::: "memory");   // this wave's stage done
        bf16x8 af[4], bf[4];
        #pragma unroll
        for (int mt = 0; mt < 4; ++mt) {
            int row = mt * 16 + l15;
            int pos = quad ^ ((row >> 1) & 3);
            af[mt] = *(const bf16x8*)(const void*)(AsW + row * 32 + pos * 8);
        }
        if (k0 + 32 < 256) {
            // af values must be in registers before overwriting the quarter
            asm volatile("s_waitcnt lgkmcnt(0)" ::: "memory");
            __builtin_amdgcn_sched_barrier(0);
            STAGE_A(k0 + 32);          // overlaps with bf reads + MFMAs below
        }
        #pragma unroll
        for (int nt = 0; nt < 4; ++nt) {
            int row = nt * 16 + l15;
            int pos = ((k0 >> 3) + quad) ^ (row & 7);
            bf[nt] = *(const bf16x8*)(const void*)(BsU + row * 256 + pos * 8);
        }
        #pragma unroll
        for (int mt = 0; mt < 4; ++mt)
            #pragma unroll
            for (int nt = 0; nt < 4; ++nt)
                acc[mt][nt] = __builtin_amdgcn_mfma_f32_16x16x32_bf16(af[mt], bf[nt], acc[mt][nt], 0, 0, 0);
    }
#undef STAGE_A

    // wsum for this thread's 4 p-columns (from LDS, un-aliased region)
    float wv[4];
    #pragma unroll
    for (int nt = 0; nt < 4; ++nt)
        wv[nt] = wsumL[nt * 16 + l15];

    // epilogue: D row = quad*4+reg (o), col = l15 (p); fp32 out + bias*wsum
    #pragma unroll
    for (int mt = 0; mt < 4; ++mt) {
        int ob = wm + mt * 16 + quad * 4;
        #pragma unroll
        for (int reg = 0; reg < 4; ++reg) {
            int o = ob + reg;
            float bias = bc[o];
            float* dst = out + ((size_t)b * 256 + o) * HW + p0 + l15;
            #pragma unroll
            for (int nt = 0; nt < 4; ++nt)
                dst[nt * 16] = acc[mt][nt][reg] + bias * wv[nt];
        }
    }
}

// ---------------------------------------------------------------------------
extern "C" void kernel_launch(void* const* d_in, const int* in_sizes, int n_in,
                              void* d_out, int out_size, void* d_ws, size_t ws_size,
                              hipStream_t stream)
{
    const float* x    = (const float*)d_in[0];
    const float* Wc   = (const float*)d_in[1];
    const float* bc   = (const float*)d_in[2];
    const float* Woff = (const float*)d_in[3];
    const float* boff = (const float*)d_in[4];
    const float* Wwt  = (const float*)d_in[5];
    const float* bwt  = (const float*)d_in[6];
    float* out = (float*)d_out;

    char* ws = (char*)d_ws;
    unsigned short* xbt  = (unsigned short*)(ws);               // 37748736 B
    float2* coords       = (float2*)(ws + 37748736);            // 2359296 B
    float*  wts          = (float*)(ws + 40108032);             // 1179648 B
    unsigned short* Wcb  = (unsigned short*)(ws + 41287680);    // 131072 B

    prep_kernel<<<dim3(NB * 144 + 32), dim3(512), 0, stream>>>(
        x, Wc, Woff, boff, Wwt, bwt, xbt, Wcb, coords, wts);
    fused_kernel<<<dim3(NB * 144), dim3(256), 0, stream>>>(
        Wcb, xbt, coords, wts, bc, out);
}

// Round 11
// 179.103 us; speedup vs baseline: 1.1651x; 1.1651x over previous
//
#include <hip/hip_runtime.h>

#define HW   9216
#define IMG  96
#define NB   8
#define NK   4

typedef __bf16 bf16x8 __attribute__((ext_vector_type(8)));
typedef float  f32x4  __attribute__((ext_vector_type(4)));

__device__ __forceinline__ unsigned short f2bf(float f) {
    unsigned int u = __float_as_uint(f);
    u += 0x7FFFu + ((u >> 16) & 1u);   // round-to-nearest-even (finite inputs)
    return (unsigned short)(u >> 16);
}

// ---------------------------------------------------------------------------
// Kernel 1: prep (+ folded Wc->bf16 conversion in trailing 32 blocks).
// EXACT r9 version (512 threads, 8-deep load batches; measured ~42-43 us).
// ---------------------------------------------------------------------------
extern "C" __global__ __launch_bounds__(512, 8)
void prep_kernel(const float* __restrict__ x,
                 const float* __restrict__ Wc,
                 const float* __restrict__ Woff,
                 const float* __restrict__ boff,
                 const float* __restrict__ Wwt,
                 const float* __restrict__ bwt,
                 unsigned short* __restrict__ xbt,
                 unsigned short* __restrict__ Wcb,
                 float2* __restrict__ coords,
                 float* __restrict__ wts)
{
    __shared__ __align__(16) unsigned short tile[64 * 266];   // 34048 B

    const int t   = threadIdx.x;
    const int bxr = blockIdx.x;

    if (bxr >= NB * 144) {
        // Wc fp32 -> bf16, row-major [o][c]. 65536 floats / (512*4) = 32 blocks.
        int u = ((bxr - NB * 144) * 512 + t) * 4;
        float4 v = *(const float4*)(Wc + u);
        union { unsigned short h[4]; int2 p; } pk;
        pk.h[0] = f2bf(v.x); pk.h[1] = f2bf(v.y);
        pk.h[2] = f2bf(v.z); pk.h[3] = f2bf(v.w);
        *(int2*)(Wcb + u) = pk.p;
        return;
    }

    const int b  = bxr / 144;
    const int p0 = (bxr % 144) * 64;
    const int px = t & 63;
    const int g  = __builtin_amdgcn_readfirstlane(t >> 6);  // wave strip 0..7

    float acc[12];
    #pragma unroll
    for (int j = 0; j < 12; ++j) acc[j] = 0.f;

    const float* xb = x + ((size_t)(b * 256 + g * 32)) * HW + p0 + px;
    unsigned int* trow = (unsigned int*)tile;

    for (int i0 = 0; i0 < 32; i0 += 8) {
        float v[8];
        #pragma unroll
        for (int q = 0; q < 8; ++q)
            v[q] = xb[(size_t)(i0 + q) * HW];     // 8 independent loads in flight
        #pragma unroll
        for (int q = 0; q < 8; ++q) {
            const int c = g * 32 + i0 + q;        // wave-uniform -> scalar wt loads
            #pragma unroll
            for (int j = 0; j < 8; ++j) acc[j] += v[q] * Woff[j * 256 + c];
            #pragma unroll
            for (int j = 0; j < 4; ++j) acc[8 + j] += v[q] * Wwt[j * 256 + c];
        }
        #pragma unroll
        for (int q = 0; q < 8; q += 2) {
            unsigned int pk = (unsigned int)f2bf(v[q]) | ((unsigned int)f2bf(v[q + 1]) << 16);
            trow[px * 133 + ((g * 32 + i0 + q) >> 1)] = pk;
        }
    }

    __syncthreads();
    // pack xbt: 64 px x 256 c bf16, int4 stores (lanes 0-31 = contiguous 512 B)
    #pragma unroll
    for (int r = 0; r < 4; ++r) {
        int u = t + 512 * r;
        int sub = u & 31, p2 = u >> 5;
        int4 v = *(const int4*)(tile + p2 * 266 + sub * 8);
        *(int4*)(xbt + ((size_t)b * HW + p0 + p2) * 256 + sub * 8) = v;
    }
    __syncthreads();

    // cross-wave partial-dot reduction through re-used tile memory (24576 B)
    float* red = (float*)tile;
    #pragma unroll
    for (int j = 0; j < 12; ++j)
        red[(g * 64 + px) * 12 + j] = acc[j];
    __syncthreads();

    if (t < 64) {
        float s[12];
        #pragma unroll
        for (int j = 0; j < 12; ++j) {
            float sj = 0.f;
            #pragma unroll
            for (int w = 0; w < 8; ++w)
                sj += red[(w * 64 + px) * 12 + j];
            s[j] = sj;
        }

        const int p = p0 + px;
        const float pyf = (float)(p / IMG);
        const float pxf = (float)(p % IMG);

        #pragma unroll
        for (int k = 0; k < NK; ++k) {
            float fx = s[k * 2 + 0] + boff[k * 2 + 0];
            float fy = s[k * 2 + 1] + boff[k * 2 + 1];
            float vx = 2.0f * (pxf + fx) / 95.0f - 1.0f;
            float vy = 2.0f * (pyf + fy) / 95.0f - 1.0f;
            float ix = (vx + 1.0f) * 48.0f - 0.5f;
            float iy = (vy + 1.0f) * 48.0f - 0.5f;
            coords[((size_t)k * NB + b) * HW + p] = make_float2(ix, iy);
        }
        float l0 = s[8] + bwt[0], l1 = s[9] + bwt[1];
        float l2 = s[10] + bwt[2], l3 = s[11] + bwt[3];
        float m = fmaxf(fmaxf(l0, l1), fmaxf(l2, l3));
        float e0 = __expf(l0 - m), e1 = __expf(l1 - m);
        float e2 = __expf(l2 - m), e3 = __expf(l3 - m);
        float inv = 1.0f / (e0 + e1 + e2 + e3);
        wts[((size_t)0 * NB + b) * HW + p] = e0 * inv;
        wts[((size_t)1 * NB + b) * HW + p] = e1 * inv;
        wts[((size_t)2 * NB + b) * HW + p] = e2 * inv;
        wts[((size_t)3 * NB + b) * HW + p] = e3 * inv;
    }
}

// ---------------------------------------------------------------------------
// Kernel 2 (FUSED sample+gemm), v8: r9 structure at 512 threads / 8 waves.
//   Latency hiding from WAVES, not registers (r8/r10 lesson: the allocator
//   targets ~6 waves/EU and spills register double-buffers).
//   - Phase B: 16 px-slots x 32 ch, 4 reps of the proven v[16] batch.
//   - Phase C: 8 waves x 32 o-rows, acc[2][4] (32 accum regs), wave-local
//     2KB As quarter, per-wave s_waitcnt, barrier-free (r7-verified scheme).
//   - LDS 49408 B -> 2 blocks x 8 waves = 16 waves/CU (was 12).
// ---------------------------------------------------------------------------
extern "C" __global__ __launch_bounds__(512, 4)
void fused_kernel(const unsigned short* __restrict__ Wcb,
                  const unsigned short* __restrict__ xbt,
                  const float2* __restrict__ coords,
                  const float* __restrict__ wts,
                  const float* __restrict__ bc,
                  float* __restrict__ out)
{
    __shared__ __align__(16) unsigned char lds[49408];
    unsigned short* BsU   = (unsigned short*)lds;             // [64][256] bf16 swz
    unsigned short* AsU   = (unsigned short*)(lds + 32768);   // 8 x [32][32] per-wave
    float*          cw    = (float*)(lds + 32768);            // [64][16] w   (A/B, aliases As)
    unsigned int*   ci    = (unsigned int*)(lds + 36864);     // [64][8] idx  (A/B, aliases As)
    float*          wsumL = (float*)(lds + 49152);            // [64] (NOT aliased)

    const int t  = threadIdx.x;
    const int bx = blockIdx.x;
    const int b  = bx & 7;            // XCD-chunked: one batch per XCD
    const int p0 = (bx >> 3) * 64;    // p tile (o tile = full 256)

    // ---------------- phase A: per-(pixel,k) coords/weights ----------------
    if (t < 256) {
        const int px = t & 63;
        const int k  = t >> 6;
        const int p  = p0 + px;
        float2 cc = coords[((size_t)k * NB + b) * HW + p];
        float wk  = wts[((size_t)k * NB + b) * HW + p];
        float x0f = floorf(cc.x), y0f = floorf(cc.y);
        float wx1 = cc.x - x0f, wx0 = 1.0f - wx1;
        float wy1 = cc.y - y0f, wy0 = 1.0f - wy1;
        int x0 = (int)x0f, y0 = (int)y0f;
        int x1 = x0 + 1,   y1 = y0 + 1;
        float vx0 = (x0 >= 0 && x0 < IMG) ? 1.f : 0.f;
        float vx1 = (x1 >= 0 && x1 < IMG) ? 1.f : 0.f;
        float vy0 = (y0 >= 0 && y0 < IMG) ? 1.f : 0.f;
        float vy1 = (y1 >= 0 && y1 < IMG) ? 1.f : 0.f;
        int cx0 = min(max(x0, 0), IMG - 1), cx1 = min(max(x1, 0), IMG - 1);
        int cy0 = min(max(y0, 0), IMG - 1), cy1 = min(max(y1, 0), IMG - 1);
        int i0 = cy0 * IMG + cx0, i1 = cy0 * IMG + cx1;
        int i2 = cy1 * IMG + cx0, i3 = cy1 * IMG + cx1;
        float w0 = wk * wx0 * wy0 * vx0 * vy0;
        float w1 = wk * wx1 * wy0 * vx1 * vy0;
        float w2 = wk * wx0 * wy1 * vx0 * vy1;
        float w3 = wk * wx1 * wy1 * vx1 * vy1;
        *(float4*)(cw + px * 16 + k * 4) = make_float4(w0, w1, w2, w3);
        uint2 ip;
        ip.x = (unsigned int)i0 | ((unsigned int)i1 << 16);
        ip.y = (unsigned int)i2 | ((unsigned int)i3 << 16);
        *(uint2*)(ci + px * 8 + k * 2) = ip;
    }
    __syncthreads();

    // ---------------- phase B: gather -> Bs (swizzled), wsum ---------------
    {
        if (t < 64) {
            float s = 0.f;
            #pragma unroll
            for (int j = 0; j < 16; ++j) s += cw[t * 16 + j];
            wsumL[t] = s;
        }
        const int pxl = t >> 5, ch = t & 31;   // 16 px-slots x 32 ch
        const unsigned short* gbase = xbt + (size_t)b * HW * 256 + ch * 8;
        #pragma unroll 2
        for (int rep = 0; rep < 4; ++rep) {
            const int px = rep * 16 + pxl;
            float wl[16];
            #pragma unroll
            for (int q = 0; q < 4; ++q) {
                float4 wv = *(const float4*)(cw + px * 16 + q * 4);
                wl[q * 4 + 0] = wv.x; wl[q * 4 + 1] = wv.y;
                wl[q * 4 + 2] = wv.z; wl[q * 4 + 3] = wv.w;
            }
            unsigned int ip[8];
            #pragma unroll
            for (int q = 0; q < 2; ++q) {
                uint4 iv = *(const uint4*)(ci + px * 8 + q * 4);
                ip[q * 4 + 0] = iv.x; ip[q * 4 + 1] = iv.y;
                ip[q * 4 + 2] = iv.z; ip[q * 4 + 3] = iv.w;
            }
            int4 v[16];
            #pragma unroll
            for (int j = 0; j < 16; ++j) {
                unsigned int idx = (ip[j >> 1] >> ((j & 1) * 16)) & 0xFFFFu;
                v[j] = *(const int4*)(gbase + (size_t)idx * 256);
            }
            float acc[8];
            #pragma unroll
            for (int i = 0; i < 8; ++i) acc[i] = 0.f;
            #pragma unroll
            for (int j = 0; j < 16; ++j) {
                const unsigned int* u = (const unsigned int*)&v[j];
                float wj = wl[j];
                #pragma unroll
                for (int q = 0; q < 4; ++q) {
                    float lo = __uint_as_float(u[q] << 16);
                    float hi = __uint_as_float(u[q] & 0xFFFF0000u);
                    acc[2 * q + 0] += wj * lo;
                    acc[2 * q + 1] += wj * hi;
                }
            }
            union { unsigned short h[8]; int4 v4; } pk;
            #pragma unroll
            for (int i = 0; i < 8; ++i) pk.h[i] = f2bf(acc[i]);
            const int pos = ch ^ (px & 7);
            *(int4*)(BsU + px * 256 + pos * 8) = pk.v4;
        }
    }
    __syncthreads();   // cw/ci dead; Bs complete. NO MORE BARRIERS below.

    // ---------------- phase C: barrier-free K-loop, wave-local As ----------
    const int lane = t & 63, wave = t >> 6;   // 8 waves
    const int wm = wave * 32;                 // this wave's 32 o-rows
    const int l15 = lane & 15, quad = lane >> 4;

    // this wave's private As quarter: [32 rows][32 k] bf16 = 2 KB
    unsigned short* AsW = AsU + wave * 1024;

    f32x4 acc[2][4];
    #pragma unroll
    for (int mt = 0; mt < 2; ++mt)
        #pragma unroll
        for (int nt = 0; nt < 4; ++nt)
            acc[mt][nt] = (f32x4){0.f, 0.f, 0.f, 0.f};

    // stage: 32 rows x 32 k = 2KB = 128 chunks x 16B, 2 insts/lane.
    // LDS dest linear (wave base + lane*16); source chunk preswizzled so
    // read slot s holds global chunk s ^ ((row>>1)&3).
#define STAGE_A(K0)                                                            \
    do {                                                                       \
        _Pragma("unroll")                                                      \
        for (int i_ = 0; i_ < 2; ++i_) {                                       \
            int u_ = lane + 64 * i_;                                           \
            int row_ = u_ >> 2, sub_ = u_ & 3;                                 \
            int subg_ = sub_ ^ ((row_ >> 1) & 3);                              \
            __builtin_amdgcn_global_load_lds(                                  \
                (const __attribute__((address_space(1))) void*)(               \
                    Wcb + (size_t)(wm + row_) * 256 + (K0) + subg_ * 8),       \
                (__attribute__((address_space(3))) void*)(AsW + u_ * 8),       \
                16, 0, 0);                                                     \
        }                                                                      \
    } while (0)

    STAGE_A(0);
    for (int k0 = 0; k0 < 256; k0 += 32) {
        asm volatile("s_waitcnt vmcnt(0)" ::: "memory");   // this wave's stage done
        bf16x8 af[2], bf[4];
        #pragma unroll
        for (int mt = 0; mt < 2; ++mt) {
            int row = mt * 16 + l15;
            int pos = quad ^ ((row >> 1) & 3);
            af[mt] = *(const bf16x8*)(const void*)(AsW + row * 32 + pos * 8);
        }
        if (k0 + 32 < 256) {
            // af values must be in registers before overwriting the quarter
            asm volatile("s_waitcnt lgkmcnt(0)" ::: "memory");
            __builtin_amdgcn_sched_barrier(0);
            STAGE_A(k0 + 32);          // overlaps with bf reads + MFMAs below
        }
        #pragma unroll
        for (int nt = 0; nt < 4; ++nt) {
            int row = nt * 16 + l15;
            int pos = ((k0 >> 3) + quad) ^ (row & 7);
            bf[nt] = *(const bf16x8*)(const void*)(BsU + row * 256 + pos * 8);
        }
        #pragma unroll
        for (int mt = 0; mt < 2; ++mt)
            #pragma unroll
            for (int nt = 0; nt < 4; ++nt)
                acc[mt][nt] = __builtin_amdgcn_mfma_f32_16x16x32_bf16(af[mt], bf[nt], acc[mt][nt], 0, 0, 0);
    }
#undef STAGE_A

    // wsum for this thread's 4 p-columns (from LDS, un-aliased region)
    float wv[4];
    #pragma unroll
    for (int nt = 0; nt < 4; ++nt)
        wv[nt] = wsumL[nt * 16 + l15];

    // epilogue: D row = quad*4+reg (o), col = l15 (p); fp32 out + bias*wsum
    #pragma unroll
    for (int mt = 0; mt < 2; ++mt) {
        int ob = wm + mt * 16 + quad * 4;
        #pragma unroll
        for (int reg = 0; reg < 4; ++reg) {
            int o = ob + reg;
            float bias = bc[o];
            float* dst = out + ((size_t)b * 256 + o) * HW + p0 + l15;
            #pragma unroll
            for (int nt = 0; nt < 4; ++nt)
                dst[nt * 16] = acc[mt][nt][reg] + bias * wv[nt];
        }
    }
}

// ---------------------------------------------------------------------------
extern "C" void kernel_launch(void* const* d_in, const int* in_sizes, int n_in,
                              void* d_out, int out_size, void* d_ws, size_t ws_size,
                              hipStream_t stream)
{
    const float* x    = (const float*)d_in[0];
    const float* Wc   = (const float*)d_in[1];
    const float* bc   = (const float*)d_in[2];
    const float* Woff = (const float*)d_in[3];
    const float* boff = (const float*)d_in[4];
    const float* Wwt  = (const float*)d_in[5];
    const float* bwt  = (const float*)d_in[6];
    float* out = (float*)d_out;

    char* ws = (char*)d_ws;
    unsigned short* xbt  = (unsigned short*)(ws);               // 37748736 B
    float2* coords       = (float2*)(ws + 37748736);            // 2359296 B
    float*  wts          = (float*)(ws + 40108032);             // 1179648 B
    unsigned short* Wcb  = (unsigned short*)(ws + 41287680);    // 131072 B

    prep_kernel<<<dim3(NB * 144 + 32), dim3(512), 0, stream>>>(
        x, Wc, Woff, boff, Wwt, bwt, xbt, Wcb, coords, wts);
    fused_kernel<<<dim3(NB * 144), dim3(512), 0, stream>>>(
        Wcb, xbt, coords, wts, bc, out);
}